// Round 2
// baseline (69.464 us; speedup 1.0000x reference)
//
#include <hip/hip_runtime.h>

// SLayer: out[b,n] = sum_p exp(-sum_d (c[n,d]-x[b,p,d])^2 * s[n,d]^2) * mask[b,p]
// B=128, P=4096, N=64, D=2.  lane == n (N==64).
// v3: in-register point broadcast via v_readlane. Lane i loads point i
//     (coalesced float2), inner loop broadcasts each point to all lanes as
//     SGPRs -- no LDS traffic, no ds_read return-path serialization
//     (~12cyc/b128 * 1536/CU = 7.7us in v2), no pre-compute barrier.
//     Mask folded into coords at stage time (m==0 -> x,y=1e18; valid since
//     w = s^2*log2e > 0 here), making the per-point mask broadcast free.
// Exponent in Horner form:
//   -dist*log2e = (A0*x+B0)*x + (A1*y+B1)*y + E,  A=-w, B=2wc, E=-(w0c0^2+w1c1^2)
// -> 2 readlane + 4 fma + 1 add + 1 v_exp_f32 per point per wave.

constexpr int B_ = 128;
constexpr int P_ = 4096;
constexpr int N_ = 64;
constexpr int CPB = 16;                // p-chunks (blocks) per batch item
constexpr int THREADS = 256;           // 4 waves
constexpr int WAVES = THREADS / 64;
constexpr int PTS_PER_BLOCK = P_ / CPB;              // 256
constexpr int PTS_PER_WAVE  = PTS_PER_BLOCK / WAVES; // 64

#if __has_builtin(__builtin_amdgcn_exp2f)
#define EXP2(x) __builtin_amdgcn_exp2f(x)
#else
#define EXP2(x) exp2f(x)
#endif

static __device__ __forceinline__ float rdlane(float v, int l) {
    return __int_as_float(__builtin_amdgcn_readlane(__float_as_int(v), l));
}

__global__ __launch_bounds__(THREADS, 8) void slayer_stage1(
    const float* __restrict__ batch,    // [B,P,2]
    const float* __restrict__ ndp,      // [B,P]
    const float* __restrict__ centers,  // [N,2]
    const float* __restrict__ sharp,    // [N,2]
    float* __restrict__ partial)        // [B,CPB,N]
{
    const int tid  = threadIdx.x;
    const int lane = tid & 63;          // lane == n
    const int wave = tid >> 6;
    const int b     = blockIdx.x / CPB;
    const int chunk = blockIdx.x % CPB;
    const int p0 = chunk * PTS_PER_BLOCK + wave * PTS_PER_WAVE;

    // ---- per-lane point: lane i owns point p0+i (coalesced loads) ----
    const float2 q = reinterpret_cast<const float2*>(batch)[(size_t)b * P_ + p0 + lane];
    const float  m = ndp[(size_t)b * P_ + p0 + lane];
    float px = q.x, py = q.y;
    if (m == 0.f) { px = 1e18f; py = 1e18f; }   // mask fold (w>0 => exp2 -> 0)

    // ---- per-lane n constants (n == lane) ----
    const float2 cc = reinterpret_cast<const float2*>(centers)[lane];
    const float2 ss = reinterpret_cast<const float2*>(sharp)[lane];
    constexpr float LOG2E = 1.44269504088896340736f;
    const float w0 = ss.x * ss.x * LOG2E;
    const float w1 = ss.y * ss.y * LOG2E;
    const float A0 = -w0,           A1 = -w1;
    const float B0 = 2.f*w0*cc.x,   B1 = 2.f*w1*cc.y;
    const float E  = -(w0*cc.x*cc.x + w1*cc.y*cc.y);

    // ---- compute: broadcast each point from its owner lane's registers ----
    float acc0 = 0.f, acc1 = 0.f;       // two chains (even/odd points) for ILP
    #pragma unroll
    for (int i = 0; i < PTS_PER_WAVE; i += 2) {
        const float x0 = rdlane(px, i),     y0 = rdlane(py, i);
        const float x1 = rdlane(px, i + 1), y1 = rdlane(py, i + 1);

        float t0 = fmaf(A0, x0, B0), t1 = fmaf(A1, y0, B1);
        float u0 = fmaf(t0, x0, E);  u0 = fmaf(t1, y0, u0);

        float r0 = fmaf(A0, x1, B0), r1 = fmaf(A1, y1, B1);
        float u1 = fmaf(r0, x1, E);  u1 = fmaf(r1, y1, u1);

        acc0 += EXP2(u0);
        acc1 += EXP2(u1);
    }

    // combine the block's 4 waves; lane l of every wave holds n==l
    __shared__ float red[THREADS];
    red[tid] = acc0 + acc1;
    __syncthreads();
    if (tid < 64) {
        partial[(size_t)blockIdx.x * N_ + tid] =
            red[tid] + red[tid + 64] + red[tid + 128] + red[tid + 192];
    }
}

__global__ __launch_bounds__(256) void slayer_stage2(
    const float* __restrict__ partial,  // [B,CPB,N]
    float* __restrict__ out)            // [B,N]
{
    const int idx = blockIdx.x * 256 + threadIdx.x;   // 0..B*N
    const int b = idx >> 6;
    const int n = idx & 63;
    const float* p = partial + (size_t)b * CPB * N_ + n;
    float s = 0.f;
    #pragma unroll
    for (int c = 0; c < CPB; ++c) s += p[c * N_];
    out[idx] = s;
}

extern "C" void kernel_launch(void* const* d_in, const int* in_sizes, int n_in,
                              void* d_out, int out_size, void* d_ws, size_t ws_size,
                              hipStream_t stream) {
    const float* batch   = (const float*)d_in[0];   // [128,4096,2]
    const float* ndp     = (const float*)d_in[1];   // [128,4096]
    const float* centers = (const float*)d_in[2];   // [64,2]
    const float* sharp   = (const float*)d_in[3];   // [64,2]
    float* out     = (float*)d_out;                 // [128,64] fp32
    float* partial = (float*)d_ws;                  // [128,16,64] = 512 KB

    slayer_stage1<<<dim3(B_ * CPB), THREADS, 0, stream>>>(batch, ndp, centers, sharp, partial);
    slayer_stage2<<<dim3((B_ * N_) / 256), 256, 0, stream>>>(partial, out);
}